// Round 10
// baseline (205.975 us; speedup 1.0000x reference)
//
#include <hip/hip_runtime.h>

#define CH 32     // bracket chunk = 32 steps (exactness: P(no merge) ~ 3e-7)
#define HCH 16    // p3 half-chunk = 16 steps (parallelism)
#define TPB 256
#define POISON_BASE 0xAAAAAAAAu   // d_ws is re-poisoned to 0xAA before every launch

// Reference step: s <- sigmoid(10*((s + u) - 0.5)) — identical ops/order to
// the PASSED R2/R7/R8/R9 kernels (absmax 0.0078 vs 0.1575 threshold).
// Monotone non-decreasing in s => bracket squeeze is exact: if trajectories
// from lo and 1 land on identical floats at step k, ANY start in [lo,1] does
// too. lo=0 for chunks>=1 (incoming is a sigmoid output); lo=-1 for chunk 0
// (net0 in (-1,1]).
__device__ __forceinline__ float sig10(float s, float u) {
    float t = (s + u) - 0.5f;
    float a = 10.0f * t;
    float e = __expf(-a);
    return 1.0f / (1.0f + e);   // IEEE divide: monotone
}

__device__ __forceinline__ void step3(float& s0, float& s1, float& s2,
                                      float u0, float u1, float u2) {
    s0 = sig10(s0, u0); s1 = sig10(s1, u1); s2 = sig10(s2, u2);
}

// ---- Phase 1 (+ folded repair): bracket each chunk. Emits:
//  state_in[c+1] : end-state (exact iff flags[c]==0)
//  state_mid[c]  : step-16 state, NaN-sentinel if brackets not merged by 16
//  flags[c], blockflags[b] : repair bookkeeping
// The LAST block to finish (device atomic on a poison-initialized counter)
// scans blockflags and serially repairs flagged chunks (exact, ~never taken).
__global__ void __launch_bounds__(TPB, 2) p1_bracket(
    const float* __restrict__ update, const float* __restrict__ net0,
    float* __restrict__ state_in, float* __restrict__ state_mid,
    int* __restrict__ flags, int* __restrict__ blockflags,
    unsigned* __restrict__ ctr, int C, int N, int nblk) {
  __shared__ int s_w[TPB / 64];
  __shared__ unsigned s_old;
  __shared__ int s_any;
  const int tid = threadIdx.x;
  if (tid < TPB / 64) s_w[tid] = 0;
  __syncthreads();
  const int c = blockIdx.x * TPB + tid;
  const bool have = (c < C);
  const bool full = have && ((size_t)(c + 1) * CH <= (size_t)N);
  int flag = 0;
  bool mvalid = false;
  float a0 = 0.f, a1 = 0.f, a2 = 0.f;
  float m0 = 0.f, m1 = 0.f, m2 = 0.f;
  if (full) {
    const float4* up4 = (const float4*)(update + (size_t)c * (CH * 3));
    float4 u[24];
#pragma unroll
    for (int g = 0; g < 24; ++g) u[g] = up4[g];   // batch-issue all 24 loads
    const float lo = (c == 0) ? -1.0f : 0.0f;
    a0 = a1 = a2 = lo;
    float b0 = 1.f, b1 = 1.f, b2 = 1.f;
    bool lanem = false;   // this lane's brackets merged (sticky: equal stays equal)
    bool bdone = false;   // wave-uniform: all lanes merged
#pragma unroll
    for (int g = 0; g < 8; ++g) {
      const float4 A = u[3 * g], B = u[3 * g + 1], Cv = u[3 * g + 2];
      step3(a0, a1, a2, A.x, A.y, A.z);
      step3(a0, a1, a2, A.w, B.x, B.y);
      step3(a0, a1, a2, B.z, B.w, Cv.x);
      step3(a0, a1, a2, Cv.y, Cv.z, Cv.w);
      if (!bdone) {                 // wave-uniform early exit of upper bracket
        step3(b0, b1, b2, A.x, A.y, A.z);
        step3(b0, b1, b2, A.w, B.x, B.y);
        step3(b0, b1, b2, B.z, B.w, Cv.x);
        step3(b0, b1, b2, Cv.y, Cv.z, Cv.w);
        bool mg = (a0 == b0) && (a1 == b1) && (a2 == b2);
        lanem = lanem || mg;
        bdone = __all(mg);
      }
      if (g == 3) { m0 = a0; m1 = a1; m2 = a2; mvalid = lanem; }
    }
    flag = lanem ? 0 : 1;
  } else if (have) {
    // tail chunk (not hit for N=4194304): scalar exact path
    const float* up = update + (size_t)c * (CH * 3);
    int steps = N - c * CH;
    const float lo = (c == 0) ? -1.0f : 0.0f;
    a0 = a1 = a2 = lo;
    float b0 = 1.f, b1 = 1.f, b2 = 1.f;
    bool lanem = false;
    for (int i = 0; i < steps; ++i) {
      step3(a0, a1, a2, up[3 * i], up[3 * i + 1], up[3 * i + 2]);
      step3(b0, b1, b2, up[3 * i], up[3 * i + 1], up[3 * i + 2]);
      lanem = lanem || ((a0 == b0) && (a1 == b1) && (a2 == b2));
      if (i == HCH - 1) { m0 = a0; m1 = a1; m2 = a2; mvalid = lanem; }
    }
    flag = lanem ? 0 : 1;
  }
  if (have) {
    if (c + 1 < C) {
      state_in[(size_t)(c + 1) * 3 + 0] = a0;
      state_in[(size_t)(c + 1) * 3 + 1] = a1;
      state_in[(size_t)(c + 1) * 3 + 2] = a2;
    }
    const float nanf_ = __int_as_float(0x7fc00000);
    state_mid[(size_t)c * 3 + 0] = mvalid ? m0 : nanf_;
    state_mid[(size_t)c * 3 + 1] = mvalid ? m1 : nanf_;
    state_mid[(size_t)c * 3 + 2] = mvalid ? m2 : nanf_;
    flags[c] = flag;
  }
  unsigned long long bal = __ballot(flag != 0);
  if ((tid & 63) == 0) s_w[tid >> 6] = (bal != 0ull) ? 1 : 0;
  __syncthreads();
  if (tid == 0) {
    int bf = 0;
#pragma unroll
    for (int w = 0; w < TPB / 64; ++w) bf |= s_w[w];
    blockflags[blockIdx.x] = bf;
  }
  // ---- last-block detection (rocPRIM idiom; deadlock-free, no spinning)
  __threadfence();                  // make this block's writes device-visible
  __syncthreads();                  // all threads fenced before the signal
  if (tid == 0) { s_old = atomicAdd(ctr, 1u); s_any = 0; }
  __syncthreads();
  if (s_old == POISON_BASE + (unsigned)nblk - 1u) {
    __threadfence();                // acquire: other blocks' writes visible
    int bad = 0;
    for (int i = tid; i < nblk; i += TPB) bad |= blockflags[i];
    if (bad) atomicOr(&s_any, 1);
    __syncthreads();
    if (tid == 0 && s_any) {        // exact serial repair (~never taken)
      for (int cc = 0; cc < C; ++cc) {
        if (!flags[cc]) continue;
        float t0, t1, t2;
        if (cc == 0) { t0 = net0[0]; t1 = net0[1]; t2 = net0[2]; }
        else {
          t0 = state_in[(size_t)cc * 3 + 0];
          t1 = state_in[(size_t)cc * 3 + 1];
          t2 = state_in[(size_t)cc * 3 + 2];
        }
        const float* up = update + (size_t)cc * (CH * 3);
        int steps = min(CH, N - cc * CH);
        for (int i = 0; i < steps; ++i)
          step3(t0, t1, t2, up[3 * i], up[3 * i + 1], up[3 * i + 2]);
        if (cc + 1 < C) {
          state_in[(size_t)(cc + 1) * 3 + 0] = t0;
          state_in[(size_t)(cc + 1) * 3 + 1] = t1;
          state_in[(size_t)(cc + 1) * 3 + 2] = t2;
        }
      }
    }
  }
}

// ---- Phase 3: TWO threads per chunk (16 steps each). Even thread starts from
// state_in[c] (net0 for c==0); odd from state_mid[c] unless NaN-sentinel
// (rare ~1e-3: replay first half from state_in — exact).
__global__ void __launch_bounds__(TPB, 4) p3_emit(
    const float* __restrict__ x, const float* __restrict__ update,
    const float* __restrict__ net0, const float* __restrict__ state_in,
    const float* __restrict__ state_mid, float* __restrict__ out,
    int C, int N) {
  __shared__ float s_o[TPB * 17];   // 16 outs/thread, stride-17: 2-way banks
  const int tid = threadIdx.x;
  const int tt = blockIdx.x * TPB + tid;
  const int c = tt >> 1, h = tt & 1;
  const bool fullBlock = ((size_t)(blockIdx.x + 1) * (TPB * HCH) <= (size_t)N);
  if (fullBlock) {
    const float4* xp4 = (const float4*)(x + (size_t)c * (CH * 3)) + h * 12;
    const float4* up4 = (const float4*)(update + (size_t)c * (CH * 3)) + h * 12;
    float4 xv[12], u[12];
#pragma unroll
    for (int g = 0; g < 12; ++g) xv[g] = xp4[g];   // cold x first
#pragma unroll
    for (int g = 0; g < 12; ++g) u[g] = up4[g];    // L3-warm u second
    float s0, s1, s2;
    if (h == 0) {
      if (c == 0) { s0 = net0[0]; s1 = net0[1]; s2 = net0[2]; }
      else {
        s0 = state_in[(size_t)c * 3 + 0];
        s1 = state_in[(size_t)c * 3 + 1];
        s2 = state_in[(size_t)c * 3 + 2];
      }
    } else {
      s0 = state_mid[(size_t)c * 3 + 0];
      if (s0 == s0) {               // valid mid-state
        s1 = state_mid[(size_t)c * 3 + 1];
        s2 = state_mid[(size_t)c * 3 + 2];
      } else {                      // rare: replay first half, exact
        if (c == 0) { s0 = net0[0]; s1 = net0[1]; s2 = net0[2]; }
        else {
          s0 = state_in[(size_t)c * 3 + 0];
          s1 = state_in[(size_t)c * 3 + 1];
          s2 = state_in[(size_t)c * 3 + 2];
        }
        const float* up = update + (size_t)c * (CH * 3);
        for (int i = 0; i < HCH; ++i)
          step3(s0, s1, s2, up[3 * i], up[3 * i + 1], up[3 * i + 2]);
      }
    }
#pragma unroll
    for (int g = 0; g < 4; ++g) {   // write straight to LDS: no obuf VGPRs
      const float4 UA = u[3 * g], UB = u[3 * g + 1], UC = u[3 * g + 2];
      const float4 XA = xv[3 * g], XB = xv[3 * g + 1], XC = xv[3 * g + 2];
      step3(s0, s1, s2, UA.x, UA.y, UA.z);
      s_o[tid * 17 + g * 4 + 0] = XA.x * s0 + XA.y * s1 + XA.z * s2;
      step3(s0, s1, s2, UA.w, UB.x, UB.y);
      s_o[tid * 17 + g * 4 + 1] = XA.w * s0 + XB.x * s1 + XB.y * s2;
      step3(s0, s1, s2, UB.z, UB.w, UC.x);
      s_o[tid * 17 + g * 4 + 2] = XB.z * s0 + XB.w * s1 + XC.x * s2;
      step3(s0, s1, s2, UC.y, UC.z, UC.w);
      s_o[tid * 17 + g * 4 + 3] = XC.y * s0 + XC.z * s1 + XC.w * s2;
    }
    __syncthreads();
    float* ob = out + (size_t)blockIdx.x * (TPB * HCH);
#pragma unroll
    for (int k = 0; k < HCH; ++k) {
      int f = k * TPB + tid;        // dword index in block's 4096-float slab
      ob[f] = s_o[(f >> 4) * 17 + (f & 15)];   // 256B/wave-instr coalesced
    }
  } else if (c < C) {
    // tail (not hit for N=4194304): scalar exact path
    int steps = min(CH, N - c * CH);
    int i0 = h * HCH, i1 = min(steps, (h + 1) * HCH);
    if (i0 >= i1) return;
    float s0, s1, s2;
    bool replay = false;
    if (h == 1) {
      s0 = state_mid[(size_t)c * 3 + 0];
      if (s0 == s0) {
        s1 = state_mid[(size_t)c * 3 + 1];
        s2 = state_mid[(size_t)c * 3 + 2];
      } else replay = true;
    }
    if (h == 0 || replay) {
      if (c == 0) { s0 = net0[0]; s1 = net0[1]; s2 = net0[2]; }
      else {
        s0 = state_in[(size_t)c * 3 + 0];
        s1 = state_in[(size_t)c * 3 + 1];
        s2 = state_in[(size_t)c * 3 + 2];
      }
    }
    const float* up = update + (size_t)c * (CH * 3);
    const float* xp = x + (size_t)c * (CH * 3);
    float* op = out + (size_t)c * CH;
    if (replay)
      for (int i = 0; i < i0; ++i)
        step3(s0, s1, s2, up[3 * i], up[3 * i + 1], up[3 * i + 2]);
    for (int i = i0; i < i1; ++i) {
      step3(s0, s1, s2, up[3 * i], up[3 * i + 1], up[3 * i + 2]);
      op[i] = xp[3 * i] * s0 + xp[3 * i + 1] * s1 + xp[3 * i + 2] * s2;
    }
  }
}

extern "C" void kernel_launch(void* const* d_in, const int* in_sizes, int n_in,
                              void* d_out, int out_size, void* d_ws, size_t ws_size,
                              hipStream_t stream) {
    const float* x      = (const float*)d_in[0];   // [N,1,3]
    const float* update = (const float*)d_in[1];   // [N,3,1]
    const float* net0   = (const float*)d_in[2];   // [3,1]
    float* out = (float*)d_out;                    // [N,1]
    int N = out_size;
    int C = (N + CH - 1) / CH;
    int nblk1 = (C + TPB - 1) / TPB;               // 512 blocks
    int nblk3 = (2 * C + TPB - 1) / TPB;           // 1024 blocks

    // ws: state_in C*3 f32 | state_mid C*3 f32 | flags C | blockflags | ctr
    char* w = (char*)d_ws;
    float* state_in  = (float*)w;                  w += (size_t)C * 3 * 4;
    float* state_mid = (float*)w;                  w += (size_t)C * 3 * 4;
    int* flags       = (int*)w;                    w += (size_t)C * 4;
    int* blockflags  = (int*)w;                    w += (size_t)nblk1 * 4;
    unsigned* ctr    = (unsigned*)w;

    hipLaunchKernelGGL(p1_bracket, dim3(nblk1), dim3(TPB), 0, stream,
                       update, net0, state_in, state_mid, flags, blockflags,
                       ctr, C, N, nblk1);
    hipLaunchKernelGGL(p3_emit, dim3(nblk3), dim3(TPB), 0, stream,
                       x, update, net0, state_in, state_mid, out, C, N);
}

// Round 11
// 146.172 us; speedup vs baseline: 1.4091x; 1.4091x over previous
//
#include <hip/hip_runtime.h>

#define CH 32     // bracket chunk = 32 steps (exactness: P(no merge) ~ 3e-7)
#define HCH 16    // p3 half-chunk = 16 steps (parallelism)
#define TPB 256

// Reference step: s <- sigmoid(10*((s + u) - 0.5)) — identical ops/order to
// the PASSED R2/R7/R8/R9 kernels (absmax 0.0078 vs 0.1575 threshold).
// Monotone non-decreasing in s => bracket squeeze is exact: if trajectories
// from lo and 1 land on identical floats at step k, ANY start in [lo,1] does
// too. lo=0 for chunks>=1 (incoming is a sigmoid output); lo=-1 for chunk 0
// (net0 in (-1,1]).
__device__ __forceinline__ float sig10(float s, float u) {
    float t = (s + u) - 0.5f;
    float a = 10.0f * t;
    float e = __expf(-a);
    return 1.0f / (1.0f + e);   // IEEE divide: monotone
}

__device__ __forceinline__ void step3(float& s0, float& s1, float& s2,
                                      float u0, float u1, float u2) {
    s0 = sig10(s0, u0); s1 = sig10(s1, u1); s2 = sig10(s2, u2);
}

// ---- Phase 1: bracket each chunk. Emits:
//  state_in[c+1] : end-state (exact iff flags[c]==0)
//  state_mid[c]  : step-16 state, NaN-sentinel if brackets not merged by 16
//  flags[c], blockflags[b] : repair bookkeeping (NO fence/atomic — R10's
//  folded last-block repair cost 30-50us in device-scope __threadfence L2
//  writebacks on 8-XCD MI355X; a separate 2-4us dispatch is cheaper)
__global__ void __launch_bounds__(TPB, 3) p1_bracket(
    const float* __restrict__ update, float* __restrict__ state_in,
    float* __restrict__ state_mid, int* __restrict__ flags,
    int* __restrict__ blockflags, int C, int N) {
  __shared__ int s_w[TPB / 64];
  const int tid = threadIdx.x;
  if (tid < TPB / 64) s_w[tid] = 0;
  __syncthreads();
  const int c = blockIdx.x * TPB + tid;
  const bool have = (c < C);
  const bool full = have && ((size_t)(c + 1) * CH <= (size_t)N);
  int flag = 0;
  bool mvalid = false;
  float a0 = 0.f, a1 = 0.f, a2 = 0.f;
  float m0 = 0.f, m1 = 0.f, m2 = 0.f;
  if (full) {
    const float4* up4 = (const float4*)(update + (size_t)c * (CH * 3));
    float4 u[24];
#pragma unroll
    for (int g = 0; g < 24; ++g) u[g] = up4[g];   // batch-issue all 24 loads
    const float lo = (c == 0) ? -1.0f : 0.0f;
    a0 = a1 = a2 = lo;
    float b0 = 1.f, b1 = 1.f, b2 = 1.f;
    bool lanem = false;   // this lane's brackets merged (sticky: equal stays equal)
    bool bdone = false;   // wave-uniform: all lanes merged
#pragma unroll
    for (int g = 0; g < 8; ++g) {
      const float4 A = u[3 * g], B = u[3 * g + 1], Cv = u[3 * g + 2];
      step3(a0, a1, a2, A.x, A.y, A.z);
      step3(a0, a1, a2, A.w, B.x, B.y);
      step3(a0, a1, a2, B.z, B.w, Cv.x);
      step3(a0, a1, a2, Cv.y, Cv.z, Cv.w);
      if (!bdone) {                 // wave-uniform early exit of upper bracket
        step3(b0, b1, b2, A.x, A.y, A.z);
        step3(b0, b1, b2, A.w, B.x, B.y);
        step3(b0, b1, b2, B.z, B.w, Cv.x);
        step3(b0, b1, b2, Cv.y, Cv.z, Cv.w);
        bool mg = (a0 == b0) && (a1 == b1) && (a2 == b2);
        lanem = lanem || mg;
        bdone = __all(mg);
      }
      if (g == 3) { m0 = a0; m1 = a1; m2 = a2; mvalid = lanem; }
    }
    flag = lanem ? 0 : 1;
  } else if (have) {
    // tail chunk (not hit for N=4194304): scalar exact path
    const float* up = update + (size_t)c * (CH * 3);
    int steps = N - c * CH;
    const float lo = (c == 0) ? -1.0f : 0.0f;
    a0 = a1 = a2 = lo;
    float b0 = 1.f, b1 = 1.f, b2 = 1.f;
    bool lanem = false;
    for (int i = 0; i < steps; ++i) {
      step3(a0, a1, a2, up[3 * i], up[3 * i + 1], up[3 * i + 2]);
      step3(b0, b1, b2, up[3 * i], up[3 * i + 1], up[3 * i + 2]);
      lanem = lanem || ((a0 == b0) && (a1 == b1) && (a2 == b2));
      if (i == HCH - 1) { m0 = a0; m1 = a1; m2 = a2; mvalid = lanem; }
    }
    flag = lanem ? 0 : 1;
  }
  if (have) {
    if (c + 1 < C) {
      state_in[(size_t)(c + 1) * 3 + 0] = a0;
      state_in[(size_t)(c + 1) * 3 + 1] = a1;
      state_in[(size_t)(c + 1) * 3 + 2] = a2;
    }
    const float nanf_ = __int_as_float(0x7fc00000);
    state_mid[(size_t)c * 3 + 0] = mvalid ? m0 : nanf_;
    state_mid[(size_t)c * 3 + 1] = mvalid ? m1 : nanf_;
    state_mid[(size_t)c * 3 + 2] = mvalid ? m2 : nanf_;
    flags[c] = flag;
  }
  unsigned long long bal = __ballot(flag != 0);
  if ((tid & 63) == 0) s_w[tid >> 6] = (bal != 0ull) ? 1 : 0;
  __syncthreads();
  if (tid == 0) {
    int bf = 0;
#pragma unroll
    for (int w = 0; w < TPB / 64; ++w) bf |= s_w[w];
    blockflags[blockIdx.x] = bf;
  }
}

// ---- Phase 2: flag scan; only if some chunk failed to collapse (p ~ 1e-8),
// serially repair flagged chunks in ascending order (exact; chunk 0 from net0).
__global__ void p2_fix(const float* __restrict__ update,
                       const float* __restrict__ net0,
                       float* __restrict__ state_in,
                       const int* __restrict__ flags,
                       const int* __restrict__ blockflags,
                       int C, int N, int NBLK) {
  __shared__ int s_any;
  if (threadIdx.x == 0) s_any = 0;
  __syncthreads();
  int bad = 0;
  for (int i = threadIdx.x; i < NBLK; i += blockDim.x) bad |= blockflags[i];
  if (bad) atomicOr(&s_any, 1);
  __syncthreads();
  if (threadIdx.x != 0) return;
  if (!s_any) return;                          // common path: nothing to do
  for (int cc = 0; cc < C; ++cc) {
    if (!flags[cc]) continue;
    float t0, t1, t2;
    if (cc == 0) { t0 = net0[0]; t1 = net0[1]; t2 = net0[2]; }
    else {
      t0 = state_in[(size_t)cc * 3 + 0];       // exact: predecessors repaired
      t1 = state_in[(size_t)cc * 3 + 1];
      t2 = state_in[(size_t)cc * 3 + 2];
    }
    const float* up = update + (size_t)cc * (CH * 3);
    int steps = min(CH, N - cc * CH);
    for (int i = 0; i < steps; ++i)
      step3(t0, t1, t2, up[3 * i], up[3 * i + 1], up[3 * i + 2]);
    if (cc + 1 < C) {
      state_in[(size_t)(cc + 1) * 3 + 0] = t0;
      state_in[(size_t)(cc + 1) * 3 + 1] = t1;
      state_in[(size_t)(cc + 1) * 3 + 2] = t2;
    }
  }
}

// ---- Phase 3: TWO threads per chunk (16 steps each). Even thread starts from
// state_in[c] (net0 for c==0); odd from state_mid[c] unless NaN-sentinel
// (rare ~1e-3: replay first half from state_in — exact).
__global__ void __launch_bounds__(TPB, 4) p3_emit(
    const float* __restrict__ x, const float* __restrict__ update,
    const float* __restrict__ net0, const float* __restrict__ state_in,
    const float* __restrict__ state_mid, float* __restrict__ out,
    int C, int N) {
  __shared__ float s_o[TPB * 17];   // 16 outs/thread, stride-17: 2-way banks
  const int tid = threadIdx.x;
  const int tt = blockIdx.x * TPB + tid;
  const int c = tt >> 1, h = tt & 1;
  const bool fullBlock = ((size_t)(blockIdx.x + 1) * (TPB * HCH) <= (size_t)N);
  if (fullBlock) {
    const float4* xp4 = (const float4*)(x + (size_t)c * (CH * 3)) + h * 12;
    const float4* up4 = (const float4*)(update + (size_t)c * (CH * 3)) + h * 12;
    float4 xv[12], u[12];
#pragma unroll
    for (int g = 0; g < 12; ++g) xv[g] = xp4[g];   // cold x first
#pragma unroll
    for (int g = 0; g < 12; ++g) u[g] = up4[g];    // L3-warm u second
    float s0, s1, s2;
    if (h == 0) {
      if (c == 0) { s0 = net0[0]; s1 = net0[1]; s2 = net0[2]; }
      else {
        s0 = state_in[(size_t)c * 3 + 0];
        s1 = state_in[(size_t)c * 3 + 1];
        s2 = state_in[(size_t)c * 3 + 2];
      }
    } else {
      s0 = state_mid[(size_t)c * 3 + 0];
      if (s0 == s0) {               // valid mid-state
        s1 = state_mid[(size_t)c * 3 + 1];
        s2 = state_mid[(size_t)c * 3 + 2];
      } else {                      // rare: replay first half, exact
        if (c == 0) { s0 = net0[0]; s1 = net0[1]; s2 = net0[2]; }
        else {
          s0 = state_in[(size_t)c * 3 + 0];
          s1 = state_in[(size_t)c * 3 + 1];
          s2 = state_in[(size_t)c * 3 + 2];
        }
        const float* up = update + (size_t)c * (CH * 3);
        for (int i = 0; i < HCH; ++i)
          step3(s0, s1, s2, up[3 * i], up[3 * i + 1], up[3 * i + 2]);
      }
    }
#pragma unroll
    for (int g = 0; g < 4; ++g) {   // write straight to LDS: no obuf VGPRs
      const float4 UA = u[3 * g], UB = u[3 * g + 1], UC = u[3 * g + 2];
      const float4 XA = xv[3 * g], XB = xv[3 * g + 1], XC = xv[3 * g + 2];
      step3(s0, s1, s2, UA.x, UA.y, UA.z);
      s_o[tid * 17 + g * 4 + 0] = XA.x * s0 + XA.y * s1 + XA.z * s2;
      step3(s0, s1, s2, UA.w, UB.x, UB.y);
      s_o[tid * 17 + g * 4 + 1] = XA.w * s0 + XB.x * s1 + XB.y * s2;
      step3(s0, s1, s2, UB.z, UB.w, UC.x);
      s_o[tid * 17 + g * 4 + 2] = XB.z * s0 + XB.w * s1 + XC.x * s2;
      step3(s0, s1, s2, UC.y, UC.z, UC.w);
      s_o[tid * 17 + g * 4 + 3] = XC.y * s0 + XC.z * s1 + XC.w * s2;
    }
    __syncthreads();
    float* ob = out + (size_t)blockIdx.x * (TPB * HCH);
#pragma unroll
    for (int k = 0; k < HCH; ++k) {
      int f = k * TPB + tid;        // dword index in block's 4096-float slab
      ob[f] = s_o[(f >> 4) * 17 + (f & 15)];   // 256B/wave-instr coalesced
    }
  } else if (c < C) {
    // tail (not hit for N=4194304): scalar exact path
    int steps = min(CH, N - c * CH);
    int i0 = h * HCH, i1 = min(steps, (h + 1) * HCH);
    if (i0 >= i1) return;
    float s0, s1, s2;
    bool replay = false;
    if (h == 1) {
      s0 = state_mid[(size_t)c * 3 + 0];
      if (s0 == s0) {
        s1 = state_mid[(size_t)c * 3 + 1];
        s2 = state_mid[(size_t)c * 3 + 2];
      } else replay = true;
    }
    if (h == 0 || replay) {
      if (c == 0) { s0 = net0[0]; s1 = net0[1]; s2 = net0[2]; }
      else {
        s0 = state_in[(size_t)c * 3 + 0];
        s1 = state_in[(size_t)c * 3 + 1];
        s2 = state_in[(size_t)c * 3 + 2];
      }
    }
    const float* up = update + (size_t)c * (CH * 3);
    const float* xp = x + (size_t)c * (CH * 3);
    float* op = out + (size_t)c * CH;
    if (replay)
      for (int i = 0; i < i0; ++i)
        step3(s0, s1, s2, up[3 * i], up[3 * i + 1], up[3 * i + 2]);
    for (int i = i0; i < i1; ++i) {
      step3(s0, s1, s2, up[3 * i], up[3 * i + 1], up[3 * i + 2]);
      op[i] = xp[3 * i] * s0 + xp[3 * i + 1] * s1 + xp[3 * i + 2] * s2;
    }
  }
}

extern "C" void kernel_launch(void* const* d_in, const int* in_sizes, int n_in,
                              void* d_out, int out_size, void* d_ws, size_t ws_size,
                              hipStream_t stream) {
    const float* x      = (const float*)d_in[0];   // [N,1,3]
    const float* update = (const float*)d_in[1];   // [N,3,1]
    const float* net0   = (const float*)d_in[2];   // [3,1]
    float* out = (float*)d_out;                    // [N,1]
    int N = out_size;
    int C = (N + CH - 1) / CH;
    int nblk1 = (C + TPB - 1) / TPB;               // 512 blocks
    int nblk3 = (2 * C + TPB - 1) / TPB;           // 1024 blocks

    // ws: state_in C*3 f32 | state_mid C*3 f32 | flags C | blockflags
    char* w = (char*)d_ws;
    float* state_in  = (float*)w;                  w += (size_t)C * 3 * 4;
    float* state_mid = (float*)w;                  w += (size_t)C * 3 * 4;
    int* flags       = (int*)w;                    w += (size_t)C * 4;
    int* blockflags  = (int*)w;

    hipLaunchKernelGGL(p1_bracket, dim3(nblk1), dim3(TPB), 0, stream,
                       update, state_in, state_mid, flags, blockflags, C, N);
    hipLaunchKernelGGL(p2_fix, dim3(1), dim3(TPB), 0, stream,
                       update, net0, state_in, flags, blockflags, C, N, nblk1);
    hipLaunchKernelGGL(p3_emit, dim3(nblk3), dim3(TPB), 0, stream,
                       x, update, net0, state_in, state_mid, out, C, N);
}